// Round 9
// baseline (76.212 us; speedup 1.0000x reference)
//
#include <hip/hip_runtime.h>

// ---------------------------------------------------------------------------
// EfficentLePE, two kernels, occupancy-first (R8 profile: 21% occupancy,
// 16% VALU, 19% HBM, 3.47M LDS conflicts -> latency-bound, L3 serves reads).
//   A[h] = softmax_e( SCALE * sum_n K[n,d] V[n,e] )   (16x16 per window/head)
//   out[n,e] = sum_d Q[n,d] A[h][d,e] + depthwise3x3(Q)[n,e] + bias
// K1: block=(window,head-pair,row-half). K/V 8-row tiles dbuf (32KB) ->
//     Gram partial -> ws.  40KB LDS, 4 blocks/CU, conflict-free reads.
// K2: block=(window,head-pair,row-quarter). A from ws (softmax, 2KB LDS,
//     ONE barrier), then conv+attn reading Q DIRECTLY from global (L2/L3):
//     no staging, no barriers, no LDS conflicts.
// ---------------------------------------------------------------------------

static constexpr int BB   = 8;
static constexpr int RES  = 128;
static constexpr int DIM  = 128;
static constexpr int WSP  = 8;
static constexpr int L    = RES * RES;   // 16384
static constexpr int ROWSTRIDE = RES * DIM;  // 16384 floats per image row
static constexpr float SCALE = 0.25f;    // HD^-0.5, HD=16

#define GLD_LDS16(g, l)                                                        \
  __builtin_amdgcn_global_load_lds(                                            \
      (const __attribute__((address_space(1))) void*)(const void*)(g),         \
      (__attribute__((address_space(3))) void*)(l), 16, 0, 0)

// ---------------------------------------------------------------------------
// K1: partial Gram (K^T V) for (window, head-pair, 64-row half) -> ws[b][512]
// ---------------------------------------------------------------------------
__global__ __launch_bounds__(256, 4) void gram_kernel(
    const float* __restrict__ Kg, const float* __restrict__ Vg,
    float* __restrict__ ws) {
  // K dbuf [0,4096) (2 x 2048), V dbuf [4096,8192), scratch [8192,10240)
  __shared__ float smem[10240];          // 40 KB

  const int b    = blockIdx.x;           // 0..1023
  const int win  = b >> 3;               // 0..127
  const int hp   = (b >> 1) & 3;         // head-pair
  const int half = b & 1;                // row half (64 rows)
  const int bi = win >> 4, wb = win & 15;
  const int t = threadIdx.x;
  const int wave = t >> 6, lane = t & 63;
  const size_t win_base = (size_t)(bi * L + wb * WSP) * DIM;
  const int ch0 = hp * 32;
  const int rbase = half * 64;

  const int h1 = lane >> 5, dq = (lane >> 3) & 3, ep = lane & 7;
  const int kaddr = h1 * 16 + dq * 4;
  const int vaddr = h1 * 16 + ep * 2;
  const int n0 = wave * 16;              // 16 tokens per wave per tile

  float a00=0.f,a01=0.f,a10=0.f,a11=0.f,a20=0.f,a21=0.f,a30=0.f,a31=0.f;

  auto stage = [&](int tile, int buf) {
    // 16 chunks (K rows 0..7, V rows 0..7), 4 per wave, 1 KB each
    for (int c = wave; c < 16; c += 4) {
      const int mat = c >> 3, rr = c & 7;
      const float* src = (mat ? Vg : Kg) + win_base +
                         (size_t)(rbase + tile * 8 + rr) * ROWSTRIDE +
                         (lane >> 3) * DIM + ch0 + (lane & 7) * 4;
      float* dst = smem + mat * 4096 + buf * 2048 + rr * 256;
      GLD_LDS16(src, dst);
    }
  };

  stage(0, 0);
  __syncthreads();
  for (int tt = 0; tt < 8; ++tt) {
    const int cur = tt & 1;
    if (tt < 7) stage(tt + 1, cur ^ 1);
    const float* Kb = smem + cur * 2048;
    const float* Vb = smem + 4096 + cur * 2048;
#pragma unroll 4
    for (int n = n0; n < n0 + 16; ++n) {
      const float4 k4 = *reinterpret_cast<const float4*>(&Kb[n * 32 + kaddr]);
      const float2 v2 = *reinterpret_cast<const float2*>(&Vb[n * 32 + vaddr]);
      a00 += k4.x * v2.x; a01 += k4.x * v2.y;
      a10 += k4.y * v2.x; a11 += k4.y * v2.y;
      a20 += k4.z * v2.x; a21 += k4.z * v2.y;
      a30 += k4.w * v2.x; a31 += k4.w * v2.y;
    }
    __syncthreads();
  }

  // per-wave partial -> scratch in NATURAL layout [h1*256 + d*16 + e]
  {
    float* sc = smem + 8192 + wave * 512 + h1 * 256 + ep * 2;
    *reinterpret_cast<float2*>(&sc[(dq * 4 + 0) * 16]) = make_float2(a00, a01);
    *reinterpret_cast<float2*>(&sc[(dq * 4 + 1) * 16]) = make_float2(a10, a11);
    *reinterpret_cast<float2*>(&sc[(dq * 4 + 2) * 16]) = make_float2(a20, a21);
    *reinterpret_cast<float2*>(&sc[(dq * 4 + 3) * 16]) = make_float2(a30, a31);
  }
  __syncthreads();

  // reduce 4 waves, write ws[b][512]
  float* wsb = ws + (size_t)b * 512;
  const float* sc = smem + 8192;
  for (int i = t; i < 512; i += 256)
    wsb[i] = sc[i] + sc[512 + i] + sc[1024 + i] + sc[1536 + i];
}

// ---------------------------------------------------------------------------
// K2: A = softmax(scaled Gram), then out = Q.A + conv3x3(Q) + bias for a
// 32-row quarter. Q read directly from global (L2/L3); no LDS after A.
// ---------------------------------------------------------------------------
__global__ __launch_bounds__(256, 3) void apply_kernel(
    const float* __restrict__ Qg, const float* __restrict__ ws,
    const float* __restrict__ cw, const float* __restrict__ cb,
    float* __restrict__ outp) {
  __shared__ float A_sm[512];

  const int b   = blockIdx.x;            // 0..2047
  const int win = b >> 4;                // 0..127
  const int hp  = (b >> 2) & 3;          // head-pair
  const int qr  = b & 3;                 // row quarter (32 rows)
  const int bi = win >> 4, wb = win & 15;
  const int t = threadIdx.x;
  const size_t win_base = (size_t)(bi * L + wb * WSP) * DIM;
  const int ch0 = hp * 32;

  // ---- reduce 2 ws partials + softmax over e -> A_sm[h*16+d][e] ----------
  {
    const float* w0 = ws + (size_t)((win * 4 + hp) * 2 + 0) * 512;
    const float* w1 = ws + (size_t)((win * 4 + hp) * 2 + 1) * 512;
    const int r = t >> 3, e2 = t & 7;    // r = h*16+d (0..31), e pair
    const int idx = r * 16 + e2 * 2;
    float v0 = (w0[idx]     + w1[idx])     * SCALE;
    float v1 = (w0[idx + 1] + w1[idx + 1]) * SCALE;
    float m = fmaxf(v0, v1);
    m = fmaxf(m, __shfl_xor(m, 1));
    m = fmaxf(m, __shfl_xor(m, 2));
    m = fmaxf(m, __shfl_xor(m, 4));
    v0 = __expf(v0 - m); v1 = __expf(v1 - m);
    float ss = v0 + v1;
    ss += __shfl_xor(ss, 1);
    ss += __shfl_xor(ss, 2);
    ss += __shfl_xor(ss, 4);
    const float ri = 1.0f / ss;
    A_sm[idx]     = v0 * ri;
    A_sm[idx + 1] = v1 * ri;
  }
  __syncthreads();                       // the ONLY barrier

  // ---- per-thread: one (row, channel-quad), all 8 window cols ------------
  const int cq = t & 7;                  // channel quad within 32
  const int lr = t >> 3;                 // 0..31
  const int hg = cq >> 2, e0 = (cq & 3) * 4;
  const int cg = ch0 + cq * 4;
  const int row = qr * 32 + lr;          // global image row

  float4 Acol[16];
#pragma unroll
  for (int d = 0; d < 16; ++d)
    Acol[d] = *reinterpret_cast<const float4*>(&A_sm[(hg * 16 + d) * 16 + e0]);
  float4 wgt[9];
#pragma unroll
  for (int tap = 0; tap < 9; ++tap) {
    wgt[tap].x = cw[(cg + 0) * 9 + tap];
    wgt[tap].y = cw[(cg + 1) * 9 + tap];
    wgt[tap].z = cw[(cg + 2) * 9 + tap];
    wgt[tap].w = cw[(cg + 3) * 9 + tap];
  }
  const float4 bias = *reinterpret_cast<const float4*>(&cb[cg]);
  const float4 zero4 = make_float4(0.f, 0.f, 0.f, 0.f);

  const bool up_ok = (row > 0), dn_ok = (row < 127);
  const float* qconv = Qg + win_base + (size_t)row * ROWSTRIDE + cg;     // dy=1
  const float* qhead = Qg + win_base + (size_t)row * ROWSTRIDE + ch0 + hg * 16;

  // rolling 3-column conv window, columns from GLOBAL (L2/L3-hot)
  auto ldcol = [&](int c, float4* dv) {
    if ((unsigned)c >= 8u) {
      dv[0] = zero4; dv[1] = zero4; dv[2] = zero4;
      return;
    }
    const float* p = qconv + c * DIM;
    dv[0] = up_ok ? *reinterpret_cast<const float4*>(p - ROWSTRIDE) : zero4;
    dv[1] = *reinterpret_cast<const float4*>(p);
    dv[2] = dn_ok ? *reinterpret_cast<const float4*>(p + ROWSTRIDE) : zero4;
  };

#define ACC(qs, d)                                                             \
  o.x += (qs) * Acol[d].x; o.y += (qs) * Acol[d].y;                            \
  o.z += (qs) * Acol[d].z; o.w += (qs) * Acol[d].w;

  float4 cL[3], cC[3], cR[3];
  ldcol(-1, cL);
  ldcol(0, cC);

#pragma unroll
  for (int wl = 0; wl < 8; ++wl) {
    ldcol(wl + 1, cR);
    float4 o = bias;
#pragma unroll
    for (int dy = 0; dy < 3; ++dy) {
      const int t0 = dy * 3;
      o.x += cL[dy].x * wgt[t0].x + cC[dy].x * wgt[t0+1].x + cR[dy].x * wgt[t0+2].x;
      o.y += cL[dy].y * wgt[t0].y + cC[dy].y * wgt[t0+1].y + cR[dy].y * wgt[t0+2].y;
      o.z += cL[dy].z * wgt[t0].z + cC[dy].z * wgt[t0+1].z + cR[dy].z * wgt[t0+2].z;
      o.w += cL[dy].w * wgt[t0].w + cC[dy].w * wgt[t0+1].w + cR[dy].w * wgt[t0+2].w;
    }
    // attention: Q[row, wl, head slice] . Acol
    {
      const float* qh = qhead + wl * DIM;
      const float4 q0 = *reinterpret_cast<const float4*>(qh + 0);
      const float4 q1 = *reinterpret_cast<const float4*>(qh + 4);
      const float4 q2 = *reinterpret_cast<const float4*>(qh + 8);
      const float4 q3 = *reinterpret_cast<const float4*>(qh + 12);
      ACC(q0.x, 0)  ACC(q0.y, 1)  ACC(q0.z, 2)  ACC(q0.w, 3)
      ACC(q1.x, 4)  ACC(q1.y, 5)  ACC(q1.z, 6)  ACC(q1.w, 7)
      ACC(q2.x, 8)  ACC(q2.y, 9)  ACC(q2.z, 10) ACC(q2.w, 11)
      ACC(q3.x, 12) ACC(q3.y, 13) ACC(q3.z, 14) ACC(q3.w, 15)
    }
    float* dst = outp + win_base + (size_t)row * ROWSTRIDE + wl * DIM + cg;
    *reinterpret_cast<float4*>(dst) = o;

#pragma unroll
    for (int dy = 0; dy < 3; ++dy) { cL[dy] = cC[dy]; cC[dy] = cR[dy]; }
  }
#undef ACC
}

// ---------------------------------------------------------------------------
extern "C" void kernel_launch(void* const* d_in, const int* in_sizes, int n_in,
                              void* d_out, int out_size, void* d_ws,
                              size_t ws_size, hipStream_t stream) {
  const float* qkv = (const float*)d_in[0];
  const float* cw  = (const float*)d_in[1];
  const float* cb  = (const float*)d_in[2];
  const float* Qg = qkv;
  const float* Kg = qkv + (size_t)BB * L * DIM;
  const float* Vg = Kg + (size_t)BB * L * DIM;
  float* ws   = (float*)d_ws;            // 1024 * 512 * 4 B = 2 MB
  float* outp = (float*)d_out;

  gram_kernel<<<1024, 256, 0, stream>>>(Kg, Vg, ws);
  apply_kernel<<<2048, 256, 0, stream>>>(Qg, ws, cw, cb, outp);
}